// Round 7
// baseline (536.356 us; speedup 1.0000x reference)
//
#include <hip/hip_runtime.h>
#include <stdint.h>

namespace {

constexpr int kBH = 128;
constexpr int kS  = 1024;
constexpr int kD  = 64;
constexpr int kQB = 32;
constexpr float kScale = 0.04419417382415922f;   // 1/sqrt(512)
constexpr float kNegInf = -3.0e38f;

typedef __attribute__((ext_vector_type(8))) short short8;   // 8 bf16
typedef __attribute__((ext_vector_type(4))) short short4v;  // 4 bf16 (8 B)
typedef __attribute__((ext_vector_type(4))) float f32x4;
typedef __attribute__((ext_vector_type(4))) int   i32x4;
typedef __attribute__((ext_vector_type(2))) unsigned int u32x2;

__device__ inline uint16_t f2bf(float f) {       // f32 -> bf16 bits, RNE
    union { float f; uint32_t u; } x; x.f = f;
    uint32_t r = x.u + 0x7fffu + ((x.u >> 16) & 1u);
    return (uint16_t)(r >> 16);
}
__device__ inline float bf2f(uint16_t h) {
    union { uint32_t u; float f; } x; x.u = ((uint32_t)h) << 16;
    return x.f;
}
__device__ inline uint32_t pkbf(float lo, float hi) {
    return (uint32_t)f2bf(lo) | ((uint32_t)f2bf(hi) << 16);
}
__device__ inline float unlo(uint32_t w) { return bf2f((uint16_t)(w & 0xffffu)); }
__device__ inline float unhi(uint32_t w) { return bf2f((uint16_t)(w >> 16)); }

// ---- prep 0: mask int32 -> 1 bit/elem. word w covers cols [32w,32w+31] ----
__global__ __launch_bounds__(256)
void pack_m_kernel(const int* __restrict__ M, uint32_t* __restrict__ Mp) {
    const size_t w = (size_t)blockIdx.x * 256 + threadIdx.x;   // word index
    const int* src = M + w * 32;                 // 128 contiguous bytes/thread
    uint32_t b = 0;
    #pragma unroll
    for (int i = 0; i < 8; ++i) {
        i32x4 m = __builtin_nontemporal_load((const i32x4*)(src + i * 4));
        b |= (m.x ? 1u : 0u) << (4 * i + 0);
        b |= (m.y ? 1u : 0u) << (4 * i + 1);
        b |= (m.z ? 1u : 0u) << (4 * i + 2);
        b |= (m.w ? 1u : 0u) << (4 * i + 3);
    }
    Mp[w] = b;
}

// ---- prep 1: K f32 [bh][k][d] -> bf16 same layout ----
__global__ __launch_bounds__(256)
void conv_k_kernel(const float* __restrict__ K, uint16_t* __restrict__ Kb) {
    const size_t base = ((size_t)blockIdx.x * 256 + threadIdx.x) * 8;
    f32x4 a = *(const f32x4*)(K + base);
    f32x4 b = *(const f32x4*)(K + base + 4);
    short8 t;
    #pragma unroll
    for (int j = 0; j < 4; ++j) { t[j] = (short)f2bf(a[j]); t[j + 4] = (short)f2bf(b[j]); }
    *(short8*)(Kb + base) = t;
}

// ---- prep 2: V f32 [bh][k][d] -> bf16 transposed Vt [bh][d][k] ----
__global__ __launch_bounds__(256)
void transp_v_kernel(const float* __restrict__ V, uint16_t* __restrict__ Vt) {
    __shared__ float t[64][65];
    const int bh = blockIdx.x >> 4;
    const int kb = blockIdx.x & 15;
    const int tid = threadIdx.x;
    const float* vb = V + ((size_t)bh * kS + kb * 64) * kD;
    #pragma unroll
    for (int rep = 0; rep < 4; ++rep) {
        const int k = (tid >> 4) + rep * 16;
        const int d4 = (tid & 15) * 4;
        f32x4 x = *(const f32x4*)(vb + (size_t)k * kD + d4);
        #pragma unroll
        for (int j = 0; j < 4; ++j) t[k][d4 + j] = x[j];
    }
    __syncthreads();
    const int d  = tid >> 2;
    const int kq = (tid & 3) * 16;
    short8 o0, o1;
    #pragma unroll
    for (int j = 0; j < 8; ++j) {
        o0[j] = (short)f2bf(t[kq + j][d]);
        o1[j] = (short)f2bf(t[kq + 8 + j][d]);
    }
    uint16_t* orow = Vt + ((size_t)bh * kD + d) * kS + kb * 64 + kq;
    *(short8*)(orow)     = o0;
    *(short8*)(orow + 8) = o1;
}

__global__ __launch_bounds__(512, 4)             // VGPR<=128, 2 WG/CU (LDS-capped)
void sdpa_kernel(const float* __restrict__ Q, const uint16_t* __restrict__ Kb,
                 const uint16_t* __restrict__ Vt, const uint32_t* __restrict__ Mp,
                 float* __restrict__ Og, float* __restrict__ Ag) {
    // P: bf16 [32][1024]; column index XOR-swizzled by (row&7)<<3
    __shared__ uint16_t P_lds[kQB * kS];         // 65536 B
    __shared__ float inv_lds[kQB];               // -> 2 WG/CU

    // XCD swizzle: 512 consecutive logical WGs (16 bh) per XCD -> Kb/Vt/Mp L2-resident
    const int logical = (blockIdx.x & 7) * 512 + (blockIdx.x >> 3);
    const int bh = logical >> 5;
    const int q0 = (logical & 31) * kQB;

    const int tid  = threadIdx.x;
    const int wave = tid >> 6;
    const int lane = tid & 63;
    const int l16  = lane & 15;
    const int lg   = lane >> 4;

    const float*    qb  = Q  + (size_t)bh * kS * kD;
    const uint16_t* kbb = Kb + (size_t)bh * kS * kD;

    // ---- Q fragments: B-operand B[k=lg*8+j][col=l16 -> q-row] ----
    short8 afr[2][2];
    #pragma unroll
    for (int m = 0; m < 2; ++m)
    #pragma unroll
    for (int ks = 0; ks < 2; ++ks) {
        const float* p = qb + (size_t)(q0 + m * 16 + l16) * kD + ks * 32 + lg * 8;
        f32x4 lo = *(const f32x4*)p;
        f32x4 hi = *(const f32x4*)(p + 4);
        short8 t;
        #pragma unroll
        for (int j = 0; j < 4; ++j) { t[j] = (short)f2bf(lo[j]); t[j + 4] = (short)f2bf(hi[j]); }
        afr[m][ks] = t;
    }

    // ---- Phase 1: S^T = K·Q^T -> lane holds 4 consecutive cols of one q-row ----
    const int n0 = wave * 128;
    #pragma unroll 2
    for (int nt = 0; nt < 8; ++nt) {
        const int nb = n0 + nt * 16;
        const uint16_t* krow = kbb + (size_t)(nb + l16) * kD + lg * 8;
        short8 kf0 = *(const short8*)(krow);
        short8 kf1 = *(const short8*)(krow + 32);
        #pragma unroll
        for (int m = 0; m < 2; ++m) {
            f32x4 acc = {0.f, 0.f, 0.f, 0.f};
            acc = __builtin_amdgcn_mfma_f32_16x16x32_bf16(kf0, afr[m][0], acc, 0, 0, 0);
            acc = __builtin_amdgcn_mfma_f32_16x16x32_bf16(kf1, afr[m][1], acc, 0, 0, 0);
            // lane: S[q=q0+m*16+l16][n=nb+lg*4+r] -> one packed b64 store
            const int rowq = m * 16 + l16;
            const int e = rowq * kS + ((nb + lg * 4) ^ ((rowq & 7) << 3));
            u32x2 w; w.x = pkbf(acc[0], acc[1]); w.y = pkbf(acc[2], acc[3]);
            *(u32x2*)(P_lds + e) = w;
        }
    }
    __syncthreads();

    // ---- Phase 2: mask(bits, L2)+scale -> max -> exp -> sum -> stores ----
    #pragma unroll
    for (int round = 0; round < 2; ++round) {
        const int row = round * 16 + (tid >> 5);  // 16 rows x 32 threads
        const int j   = tid & 31;
        const int c0  = j * 4;
        const int swz = (row & 7) << 3;
        const uint32_t* mprow = Mp + ((size_t)bh * kS + q0 + row) * 32;
        uint16_t* prow = P_lds + row * kS;

        uint32_t mwv[8];                          // 8 indep dword loads, L2-resident
        #pragma unroll
        for (int i = 0; i < 8; ++i) mwv[i] = mprow[(j >> 3) + i * 4];
        const int sh = (j & 7) * 4;

        u32x2 ps[8];
        float mx = kNegInf;
        #pragma unroll
        for (int i = 0; i < 8; ++i) {
            short4v s4 = *(const short4v*)(prow + ((c0 + i * 128) ^ swz));
            const uint32_t nib = (mwv[i] >> sh) & 0xFu;
            float v0 = (nib & 1u) ? kNegInf : bf2f((uint16_t)s4.x) * kScale;
            float v1 = (nib & 2u) ? kNegInf : bf2f((uint16_t)s4.y) * kScale;
            float v2 = (nib & 4u) ? kNegInf : bf2f((uint16_t)s4.z) * kScale;
            float v3 = (nib & 8u) ? kNegInf : bf2f((uint16_t)s4.w) * kScale;
            ps[i].x = pkbf(v0, v1); ps[i].y = pkbf(v2, v3);
            mx = fmaxf(mx, fmaxf(fmaxf(v0, v1), fmaxf(v2, v3)));
        }
        #pragma unroll
        for (int o = 16; o; o >>= 1) mx = fmaxf(mx, __shfl_xor(mx, o));

        float sum = 0.f;
        #pragma unroll
        for (int i = 0; i < 8; ++i) {
            float p0 = __expf(unlo(ps[i].x) - mx);
            float p1 = __expf(unhi(ps[i].x) - mx);
            float p2 = __expf(unlo(ps[i].y) - mx);
            float p3 = __expf(unhi(ps[i].y) - mx);
            sum += (p0 + p1) + (p2 + p3);
            u32x2 w; w.x = pkbf(p0, p1); w.y = pkbf(p2, p3);
            ps[i] = w;
            *(u32x2*)(prow + ((c0 + i * 128) ^ swz)) = w;   // unnormalized p -> LDS
        }
        #pragma unroll
        for (int o = 16; o; o >>= 1) sum += __shfl_xor(sum, o);
        const float inv = 1.0f / sum;
        if (j == 0) inv_lds[row] = inv;

        float* arow = Ag + ((size_t)bh * kS + q0 + row) * kS;
        #pragma unroll
        for (int i = 0; i < 8; ++i) {
            f32x4 a = { unlo(ps[i].x) * inv, unhi(ps[i].x) * inv,
                        unlo(ps[i].y) * inv, unhi(ps[i].y) * inv };
            *(f32x4*)(arow + c0 + i * 128) = a;             // coalesced f32x4, posted
        }
    }
    __syncthreads();

    // ---- Phase 3: O = P @ V, zero barriers; Vt b128 from L2, P b128 from LDS ----
    {
        const int m  = wave >> 2;                // 0..1
        const int d0 = (wave & 3) * 16;          // 0..48
        const uint16_t* vtrow = Vt + ((size_t)bh * kD + d0 + l16) * kS + lg * 8;
        const uint16_t* pbase = P_lds + (size_t)(m * 16 + l16) * kS;
        const int aswz = (l16 & 7) << 3;
        f32x4 acc0 = {0.f, 0.f, 0.f, 0.f};
        f32x4 acc1 = {0.f, 0.f, 0.f, 0.f};
        #pragma unroll
        for (int kk = 0; kk < 32; kk += 2) {
            short8 a0 = *(const short8*)(pbase + ((kk * 32 + lg * 8) ^ aswz));
            short8 b0 = *(const short8*)(vtrow + kk * 32);
            acc0 = __builtin_amdgcn_mfma_f32_16x16x32_bf16(a0, b0, acc0, 0, 0, 0);
            short8 a1 = *(const short8*)(pbase + (((kk + 1) * 32 + lg * 8) ^ aswz));
            short8 b1 = *(const short8*)(vtrow + (kk + 1) * 32);
            acc1 = __builtin_amdgcn_mfma_f32_16x16x32_bf16(a1, b1, acc1, 0, 0, 0);
        }
        f32x4 acc = acc0 + acc1;
        f32x4 invv = *(const f32x4*)(inv_lds + m * 16 + lg * 4);
        float* orow = Og + ((size_t)bh * kS + q0 + m * 16 + lg * 4) * kD + d0 + l16;
        #pragma unroll
        for (int r = 0; r < 4; ++r) orow[(size_t)r * kD] = acc[r] * invv[r];
    }
}

} // namespace

extern "C" void kernel_launch(void* const* d_in, const int* in_sizes, int n_in,
                              void* d_out, int out_size, void* d_ws, size_t ws_size,
                              hipStream_t stream) {
    const float* q = (const float*)d_in[0];
    const float* k = (const float*)d_in[1];
    const float* v = (const float*)d_in[2];
    const int*   m = (const int*)d_in[3];
    float* og = (float*)d_out;
    float* ag = og + (size_t)kBH * kS * kD;      // outputs concatenated: O then attn

    uint16_t* kb = (uint16_t*)d_ws;              // 16.78 MB bf16 K
    uint16_t* vt = kb + (size_t)kBH * kS * kD;   // 16.78 MB bf16 V^T [bh][d][k]
    uint32_t* mp = (uint32_t*)(vt + (size_t)kBH * kS * kD);  // 16.78 MB mask bits

    pack_m_kernel<<<dim3(16384), dim3(256), 0, stream>>>(m, mp);
    conv_k_kernel<<<dim3(4096), dim3(256), 0, stream>>>(k, kb);
    transp_v_kernel<<<dim3(2048), dim3(256), 0, stream>>>(v, vt);
    sdpa_kernel<<<dim3(kBH * (kS / kQB)), dim3(512), 0, stream>>>(q, kb, vt, mp, og, ag);
}

// Round 8
// 420.758 us; speedup vs baseline: 1.2747x; 1.2747x over previous
//
#include <hip/hip_runtime.h>
#include <stdint.h>

namespace {

constexpr int kBH = 128;
constexpr int kS  = 1024;
constexpr int kD  = 64;
constexpr int kQB = 32;
constexpr float kScale = 0.04419417382415922f;   // 1/sqrt(512)
constexpr float kNegInf = -3.0e38f;

typedef __attribute__((ext_vector_type(8))) short short8;   // 8 bf16
typedef __attribute__((ext_vector_type(4))) float f32x4;
typedef __attribute__((ext_vector_type(4))) int   i32x4;
typedef __attribute__((ext_vector_type(2))) unsigned int u32x2;

__device__ inline uint16_t f2bf(float f) {       // f32 -> bf16 bits, RNE
    union { float f; uint32_t u; } x; x.f = f;
    uint32_t r = x.u + 0x7fffu + ((x.u >> 16) & 1u);
    return (uint16_t)(r >> 16);
}
__device__ inline uint32_t pkbf(float lo, float hi) {
    return (uint32_t)f2bf(lo) | ((uint32_t)f2bf(hi) << 16);
}

// ---- prep 1: K f32 [bh][k][d] -> bf16 same layout ----
__global__ __launch_bounds__(256)
void conv_k_kernel(const float* __restrict__ K, uint16_t* __restrict__ Kb) {
    const size_t base = ((size_t)blockIdx.x * 256 + threadIdx.x) * 8;
    f32x4 a = *(const f32x4*)(K + base);
    f32x4 b = *(const f32x4*)(K + base + 4);
    short8 t;
    #pragma unroll
    for (int j = 0; j < 4; ++j) { t[j] = (short)f2bf(a[j]); t[j + 4] = (short)f2bf(b[j]); }
    *(short8*)(Kb + base) = t;
}

// ---- prep 2: V f32 [bh][k][d] -> bf16 transposed Vt [bh][d][k] ----
__global__ __launch_bounds__(256)
void transp_v_kernel(const float* __restrict__ V, uint16_t* __restrict__ Vt) {
    __shared__ float t[64][65];
    const int bh = blockIdx.x >> 4;
    const int kb = blockIdx.x & 15;
    const int tid = threadIdx.x;
    const float* vb = V + ((size_t)bh * kS + kb * 64) * kD;
    #pragma unroll
    for (int rep = 0; rep < 4; ++rep) {
        const int k = (tid >> 4) + rep * 16;
        const int d4 = (tid & 15) * 4;
        f32x4 x = *(const f32x4*)(vb + (size_t)k * kD + d4);
        #pragma unroll
        for (int j = 0; j < 4; ++j) t[k][d4 + j] = x[j];
    }
    __syncthreads();
    const int d  = tid >> 2;
    const int kq = (tid & 3) * 16;
    short8 o0, o1;
    #pragma unroll
    for (int j = 0; j < 8; ++j) {
        o0[j] = (short)f2bf(t[kq + j][d]);
        o1[j] = (short)f2bf(t[kq + 8 + j][d]);
    }
    uint16_t* orow = Vt + ((size_t)bh * kD + d) * kS + kb * 64 + kq;
    *(short8*)(orow)     = o0;
    *(short8*)(orow + 8) = o1;
}

__global__ __launch_bounds__(512, 4)             // VGPR<=128, 2 WG/CU (LDS-capped)
void sdpa_kernel(const float* __restrict__ Q, const uint16_t* __restrict__ Kb,
                 const uint16_t* __restrict__ Vt, const int* __restrict__ M,
                 float* __restrict__ Og, float* __restrict__ Ag) {
    __shared__ uint16_t P_lds[kQB * kS];         // 64 KiB: bf16 p only (XOR-swizzled)
    __shared__ float smax[kQB][8];               // cross-wave max partials
    __shared__ float ssum[kQB][8];               // cross-wave sum partials
    __shared__ float inv_lds[kQB];

    // XCD swizzle: 512 consecutive logical WGs (16 bh) per XCD -> Kb/Vt L2-resident
    const int logical = (blockIdx.x & 7) * 512 + (blockIdx.x >> 3);
    const int bh = logical >> 5;
    const int q0 = (logical & 31) * kQB;

    const int tid  = threadIdx.x;
    const int wave = tid >> 6;
    const int lane = tid & 63;
    const int l16  = lane & 15;
    const int lg   = lane >> 4;

    const float*    qb  = Q  + (size_t)bh * kS * kD;
    const uint16_t* kbb = Kb + (size_t)bh * kS * kD;

    // ---- Q fragments: B-operand B[k=lg*8+j][col=l16 -> q-row] ----
    short8 afr[2][2];
    #pragma unroll
    for (int m = 0; m < 2; ++m)
    #pragma unroll
    for (int ks = 0; ks < 2; ++ks) {
        const float* p = qb + (size_t)(q0 + m * 16 + l16) * kD + ks * 32 + lg * 8;
        f32x4 lo = *(const f32x4*)p;
        f32x4 hi = *(const f32x4*)(p + 4);
        short8 t;
        #pragma unroll
        for (int j = 0; j < 4; ++j) { t[j] = (short)f2bf(lo[j]); t[j + 4] = (short)f2bf(hi[j]); }
        afr[m][ks] = t;
    }

    // ---- Phase 1: S^T = K·Q^T, scores stay in REGISTERS ----
    // lane holds S[q=q0+m*16+l16][n0+nt*16+lg*4+r] in sc[m][nt][r]
    const int n0 = wave * 128;
    f32x4 sc[2][8];
    #pragma unroll
    for (int nt = 0; nt < 8; ++nt) {
        const int nb = n0 + nt * 16;
        const uint16_t* krow = kbb + (size_t)(nb + l16) * kD + lg * 8;
        short8 kf0 = *(const short8*)(krow);
        short8 kf1 = *(const short8*)(krow + 32);
        #pragma unroll
        for (int m = 0; m < 2; ++m) {
            f32x4 acc = {0.f, 0.f, 0.f, 0.f};
            acc = __builtin_amdgcn_mfma_f32_16x16x32_bf16(kf0, afr[m][0], acc, 0, 0, 0);
            acc = __builtin_amdgcn_mfma_f32_16x16x32_bf16(kf1, afr[m][1], acc, 0, 0, 0);
            sc[m][nt] = acc;
        }
    }

    // ---- Phase 2a: mask+scale in regs -> per-row partial max ----
    #pragma unroll
    for (int m = 0; m < 2; ++m) {
        const int* mrow = M + ((size_t)bh * kS + q0 + m * 16 + l16) * kS + n0 + lg * 4;
        i32x4 mk[8];
        #pragma unroll
        for (int nt = 0; nt < 8; ++nt)           // 8 NT b128 loads in flight
            mk[nt] = __builtin_nontemporal_load((const i32x4*)(mrow + nt * 16));
        float mx = kNegInf;
        #pragma unroll
        for (int nt = 0; nt < 8; ++nt) {
            f32x4 s = sc[m][nt];
            s.x = mk[nt].x ? kNegInf : s.x * kScale;
            s.y = mk[nt].y ? kNegInf : s.y * kScale;
            s.z = mk[nt].z ? kNegInf : s.z * kScale;
            s.w = mk[nt].w ? kNegInf : s.w * kScale;
            sc[m][nt] = s;
            mx = fmaxf(mx, fmaxf(fmaxf(s.x, s.y), fmaxf(s.z, s.w)));
        }
        mx = fmaxf(mx, __shfl_xor(mx, 16));      // reduce over lg
        mx = fmaxf(mx, __shfl_xor(mx, 32));
        if (lane < 16) smax[m * 16 + l16][wave] = mx;
    }
    __syncthreads();                              // B1

    // ---- Phase 2b: final max -> exp (in regs) -> partial sum ----
    #pragma unroll
    for (int m = 0; m < 2; ++m) {
        const float* sp = &smax[m * 16 + l16][0];
        f32x4 a = *(const f32x4*)sp;
        f32x4 b = *(const f32x4*)(sp + 4);
        const float mx = fmaxf(fmaxf(fmaxf(a.x, a.y), fmaxf(a.z, a.w)),
                               fmaxf(fmaxf(b.x, b.y), fmaxf(b.z, b.w)));
        float sum = 0.f;
        #pragma unroll
        for (int nt = 0; nt < 8; ++nt) {
            f32x4 s = sc[m][nt];
            s.x = __expf(s.x - mx);
            s.y = __expf(s.y - mx);
            s.z = __expf(s.z - mx);
            s.w = __expf(s.w - mx);
            sc[m][nt] = s;                        // unnormalized p, f32, in regs
            sum += (s.x + s.y) + (s.z + s.w);
        }
        sum += __shfl_xor(sum, 16);
        sum += __shfl_xor(sum, 32);
        if (lane < 16) ssum[m * 16 + l16][wave] = sum;
    }
    __syncthreads();                              // B2

    // ---- Phase 2c: inv -> attn f32 store (from regs) + p bf16 -> LDS ----
    #pragma unroll
    for (int m = 0; m < 2; ++m) {
        const int rowq = m * 16 + l16;
        const float* sp = &ssum[rowq][0];
        f32x4 a = *(const f32x4*)sp;
        f32x4 b = *(const f32x4*)(sp + 4);
        const float sum = ((a.x + a.y) + (a.z + a.w)) + ((b.x + b.y) + (b.z + b.w));
        const float inv = 1.0f / sum;
        if (lane < 16) inv_lds[rowq] = inv;
        float* arow = Ag + ((size_t)bh * kS + q0 + rowq) * kS + n0 + lg * 4;
        uint16_t* prow = P_lds + rowq * kS;
        const int swz = (rowq & 7) << 3;
        #pragma unroll
        for (int nt = 0; nt < 8; ++nt) {
            f32x4 s = sc[m][nt];
            f32x4 o = { s.x * inv, s.y * inv, s.z * inv, s.w * inv };
            *(f32x4*)(arow + nt * 16) = o;        // attn, f32, straight from regs
            u32x2 w; w.x = pkbf(s.x, s.y); w.y = pkbf(s.z, s.w);
            *(u32x2*)(prow + ((n0 + nt * 16 + lg * 4) ^ swz)) = w;
        }
    }
    __syncthreads();                              // B3: P + inv ready

    // ---- Phase 3: O = P @ V; Vt b128 from L2, P b128 from LDS ----
    {
        const int m  = wave >> 2;                // 0..1 (q-row half)
        const int d0 = (wave & 3) * 16;          // 0..48
        const uint16_t* vtrow = Vt + ((size_t)bh * kD + d0 + l16) * kS + lg * 8;
        const uint16_t* pbase = P_lds + (size_t)(m * 16 + l16) * kS;
        const int aswz = (l16 & 7) << 3;
        f32x4 acc0 = {0.f, 0.f, 0.f, 0.f};
        f32x4 acc1 = {0.f, 0.f, 0.f, 0.f};
        __builtin_amdgcn_s_setprio(1);
        #pragma unroll
        for (int kk = 0; kk < 32; kk += 2) {
            short8 a0 = *(const short8*)(pbase + ((kk * 32 + lg * 8) ^ aswz));
            short8 b0 = *(const short8*)(vtrow + kk * 32);
            acc0 = __builtin_amdgcn_mfma_f32_16x16x32_bf16(a0, b0, acc0, 0, 0, 0);
            short8 a1 = *(const short8*)(pbase + (((kk + 1) * 32 + lg * 8) ^ aswz));
            short8 b1 = *(const short8*)(vtrow + (kk + 1) * 32);
            acc1 = __builtin_amdgcn_mfma_f32_16x16x32_bf16(a1, b1, acc1, 0, 0, 0);
        }
        __builtin_amdgcn_s_setprio(0);
        f32x4 acc = acc0 + acc1;
        f32x4 invv = *(const f32x4*)(inv_lds + m * 16 + lg * 4);
        float* orow = Og + ((size_t)bh * kS + q0 + m * 16 + lg * 4) * kD + d0 + l16;
        #pragma unroll
        for (int r = 0; r < 4; ++r) orow[(size_t)r * kD] = acc[r] * invv[r];
    }
}

} // namespace

extern "C" void kernel_launch(void* const* d_in, const int* in_sizes, int n_in,
                              void* d_out, int out_size, void* d_ws, size_t ws_size,
                              hipStream_t stream) {
    const float* q = (const float*)d_in[0];
    const float* k = (const float*)d_in[1];
    const float* v = (const float*)d_in[2];
    const int*   m = (const int*)d_in[3];
    float* og = (float*)d_out;
    float* ag = og + (size_t)kBH * kS * kD;      // outputs concatenated: O then attn

    uint16_t* kb = (uint16_t*)d_ws;              // 16.78 MB bf16 K
    uint16_t* vt = kb + (size_t)kBH * kS * kD;   // 16.78 MB bf16 V^T [bh][d][k]

    conv_k_kernel<<<dim3(4096), dim3(256), 0, stream>>>(k, kb);
    transp_v_kernel<<<dim3(2048), dim3(256), 0, stream>>>(v, vt);
    sdpa_kernel<<<dim3(kBH * (kS / kQB)), dim3(512), 0, stream>>>(q, kb, vt, m, og, ag);
}

// Round 9
// 412.065 us; speedup vs baseline: 1.3016x; 1.0211x over previous
//
#include <hip/hip_runtime.h>
#include <stdint.h>

namespace {

constexpr int kBH = 128;
constexpr int kS  = 1024;
constexpr int kD  = 64;
constexpr int kQB = 32;
constexpr float kScale = 0.04419417382415922f;   // 1/sqrt(512)
constexpr float kNegInf = -3.0e38f;

typedef __attribute__((ext_vector_type(8))) short short8;   // 8 bf16
typedef __attribute__((ext_vector_type(4))) short short4v;  // 4 bf16 (8 B)
typedef __attribute__((ext_vector_type(4))) float f32x4;
typedef __attribute__((ext_vector_type(4))) int   i32x4;
typedef __attribute__((ext_vector_type(2))) unsigned int u32x2;

__device__ inline uint16_t f2bf(float f) {       // f32 -> bf16 bits, RNE
    union { float f; uint32_t u; } x; x.f = f;
    uint32_t r = x.u + 0x7fffu + ((x.u >> 16) & 1u);
    return (uint16_t)(r >> 16);
}
__device__ inline float bf2f(uint16_t h) {
    union { uint32_t u; float f; } x; x.u = ((uint32_t)h) << 16;
    return x.f;
}
__device__ inline uint32_t pkbf(float lo, float hi) {
    return (uint32_t)f2bf(lo) | ((uint32_t)f2bf(hi) << 16);
}

// ---- prep 1: K f32 [bh][k][d] -> bf16 same layout ----
__global__ __launch_bounds__(256)
void conv_k_kernel(const float* __restrict__ K, uint16_t* __restrict__ Kb) {
    const size_t base = ((size_t)blockIdx.x * 256 + threadIdx.x) * 8;
    f32x4 a = *(const f32x4*)(K + base);
    f32x4 b = *(const f32x4*)(K + base + 4);
    short8 t;
    #pragma unroll
    for (int j = 0; j < 4; ++j) { t[j] = (short)f2bf(a[j]); t[j + 4] = (short)f2bf(b[j]); }
    *(short8*)(Kb + base) = t;
}

// ---- prep 2: V f32 [bh][k][d] -> bf16 transposed Vt [bh][d][k] ----
__global__ __launch_bounds__(256)
void transp_v_kernel(const float* __restrict__ V, uint16_t* __restrict__ Vt) {
    __shared__ float t[64][65];
    const int bh = blockIdx.x >> 4;
    const int kb = blockIdx.x & 15;
    const int tid = threadIdx.x;
    const float* vb = V + ((size_t)bh * kS + kb * 64) * kD;
    #pragma unroll
    for (int rep = 0; rep < 4; ++rep) {
        const int k = (tid >> 4) + rep * 16;
        const int d4 = (tid & 15) * 4;
        f32x4 x = *(const f32x4*)(vb + (size_t)k * kD + d4);
        #pragma unroll
        for (int j = 0; j < 4; ++j) t[k][d4 + j] = x[j];
    }
    __syncthreads();
    const int d  = tid >> 2;
    const int kq = (tid & 3) * 16;
    short8 o0, o1;
    #pragma unroll
    for (int j = 0; j < 8; ++j) {
        o0[j] = (short)f2bf(t[kq + j][d]);
        o1[j] = (short)f2bf(t[kq + 8 + j][d]);
    }
    uint16_t* orow = Vt + ((size_t)bh * kD + d) * kS + kb * 64 + kq;
    *(short8*)(orow)     = o0;
    *(short8*)(orow + 8) = o1;
}

__global__ __launch_bounds__(512, 4)             // VGPR<=128, 2 WG/CU (LDS-capped)
void sdpa_kernel(const float* __restrict__ Q, const uint16_t* __restrict__ Kb,
                 const uint16_t* __restrict__ Vt, const int* __restrict__ M,
                 float* __restrict__ Og, float* __restrict__ Ag) {
    __shared__ uint16_t P_lds[kQB * kS];         // 64 KiB: bf16 p (XOR-swizzled)
    __shared__ float smax[kQB][8];               // cross-wave max partials
    __shared__ float ssum[kQB][8];               // cross-wave sum partials
    __shared__ float inv_lds[kQB];

    // NO XCD swizzle: consecutive blockIdx -> consecutive 128 KiB regions of
    // mask (read) and attn (write) => DRAM-sequential streams.
    const int bh = blockIdx.x >> 5;
    const int q0 = (blockIdx.x & 31) * kQB;

    const int tid  = threadIdx.x;
    const int wave = tid >> 6;
    const int lane = tid & 63;
    const int l16  = lane & 15;
    const int lg   = lane >> 4;

    const float*    qb  = Q  + (size_t)bh * kS * kD;
    const uint16_t* kbb = Kb + (size_t)bh * kS * kD;

    // ---- Q fragments: B-operand B[k=lg*8+j][col=l16 -> q-row] ----
    short8 afr[2][2];
    #pragma unroll
    for (int m = 0; m < 2; ++m)
    #pragma unroll
    for (int ks = 0; ks < 2; ++ks) {
        const float* p = qb + (size_t)(q0 + m * 16 + l16) * kD + ks * 32 + lg * 8;
        f32x4 lo = *(const f32x4*)p;
        f32x4 hi = *(const f32x4*)(p + 4);
        short8 t;
        #pragma unroll
        for (int j = 0; j < 4; ++j) { t[j] = (short)f2bf(lo[j]); t[j + 4] = (short)f2bf(hi[j]); }
        afr[m][ks] = t;
    }

    // ---- Phase 1: S^T = K·Q^T, scores stay in registers ----
    // lane holds S[q=q0+m*16+l16][n0+nt*16+lg*4+r] in sc[m][nt][r]
    const int n0 = wave * 128;
    f32x4 sc[2][8];
    #pragma unroll
    for (int nt = 0; nt < 8; ++nt) {
        const int nb = n0 + nt * 16;
        const uint16_t* krow = kbb + (size_t)(nb + l16) * kD + lg * 8;
        short8 kf0 = *(const short8*)(krow);
        short8 kf1 = *(const short8*)(krow + 32);
        #pragma unroll
        for (int m = 0; m < 2; ++m) {
            f32x4 acc = {0.f, 0.f, 0.f, 0.f};
            acc = __builtin_amdgcn_mfma_f32_16x16x32_bf16(kf0, afr[m][0], acc, 0, 0, 0);
            acc = __builtin_amdgcn_mfma_f32_16x16x32_bf16(kf1, afr[m][1], acc, 0, 0, 0);
            sc[m][nt] = acc;
        }
    }

    // ---- Phase 2a: mask+scale in regs -> per-row partial max ----
    #pragma unroll
    for (int m = 0; m < 2; ++m) {
        const int* mrow = M + ((size_t)bh * kS + q0 + m * 16 + l16) * kS + n0 + lg * 4;
        i32x4 mk[8];
        #pragma unroll
        for (int nt = 0; nt < 8; ++nt)           // 8 b128 loads in flight
            mk[nt] = *(const i32x4*)(mrow + nt * 16);
        float mx = kNegInf;
        #pragma unroll
        for (int nt = 0; nt < 8; ++nt) {
            f32x4 s = sc[m][nt];
            s.x = mk[nt].x ? kNegInf : s.x * kScale;
            s.y = mk[nt].y ? kNegInf : s.y * kScale;
            s.z = mk[nt].z ? kNegInf : s.z * kScale;
            s.w = mk[nt].w ? kNegInf : s.w * kScale;
            sc[m][nt] = s;
            mx = fmaxf(mx, fmaxf(fmaxf(s.x, s.y), fmaxf(s.z, s.w)));
        }
        mx = fmaxf(mx, __shfl_xor(mx, 16));      // reduce over lg
        mx = fmaxf(mx, __shfl_xor(mx, 32));
        if (lane < 16) smax[m * 16 + l16][wave] = mx;
    }
    __syncthreads();                              // B1

    // ---- Phase 2b: final max -> exp (in regs) -> partial sum ----
    #pragma unroll
    for (int m = 0; m < 2; ++m) {
        const float* sp = &smax[m * 16 + l16][0];
        f32x4 a = *(const f32x4*)sp;
        f32x4 b = *(const f32x4*)(sp + 4);
        const float mx = fmaxf(fmaxf(fmaxf(a.x, a.y), fmaxf(a.z, a.w)),
                               fmaxf(fmaxf(b.x, b.y), fmaxf(b.z, b.w)));
        float sum = 0.f;
        #pragma unroll
        for (int nt = 0; nt < 8; ++nt) {
            f32x4 s = sc[m][nt];
            s.x = __expf(s.x - mx);
            s.y = __expf(s.y - mx);
            s.z = __expf(s.z - mx);
            s.w = __expf(s.w - mx);
            sc[m][nt] = s;                        // unnormalized p, f32, in regs
            sum += (s.x + s.y) + (s.z + s.w);
        }
        sum += __shfl_xor(sum, 16);
        sum += __shfl_xor(sum, 32);
        if (lane < 16) ssum[m * 16 + l16][wave] = sum;
    }
    __syncthreads();                              // B2

    // ---- Phase 2c: inv -> p bf16 into LDS (swizzled) ----
    #pragma unroll
    for (int m = 0; m < 2; ++m) {
        const int rowq = m * 16 + l16;
        const float* sp = &ssum[rowq][0];
        f32x4 a = *(const f32x4*)sp;
        f32x4 b = *(const f32x4*)(sp + 4);
        const float sum = ((a.x + a.y) + (a.z + a.w)) + ((b.x + b.y) + (b.z + b.w));
        if (lane < 16) inv_lds[rowq] = 1.0f / sum;
        uint16_t* prow = P_lds + rowq * kS;
        const int swz = (rowq & 7) << 3;
        #pragma unroll
        for (int nt = 0; nt < 8; ++nt) {
            f32x4 s = sc[m][nt];
            u32x2 w; w.x = pkbf(s.x, s.y); w.y = pkbf(s.z, s.w);
            *(u32x2*)(prow + ((n0 + nt * 16 + lg * 4) ^ swz)) = w;
        }
    }
    __syncthreads();                              // B3: P + inv ready

    // ---- Phase 2d: attn store, wave-contiguous 1 KiB per instruction ----
    // wave owns rows 4w..4w+3; lane l covers cols c*256 + 4l .. +3
    #pragma unroll
    for (int r = 0; r < 4; ++r) {
        const int row = wave * 4 + r;
        const float inv = inv_lds[row];
        const uint16_t* prow = P_lds + row * kS;
        const int swz = (row & 7) << 3;
        float* arow = Ag + ((size_t)bh * kS + q0 + row) * kS;
        #pragma unroll
        for (int c = 0; c < 4; ++c) {
            const int col = c * 256 + lane * 4;
            short4v p4 = *(const short4v*)(prow + (col ^ swz));
            f32x4 a = { bf2f((uint16_t)p4.x) * inv, bf2f((uint16_t)p4.y) * inv,
                        bf2f((uint16_t)p4.z) * inv, bf2f((uint16_t)p4.w) * inv };
            *(f32x4*)(arow + col) = a;            // 64 lanes x 16 B = 1 KiB contiguous
        }
    }

    // ---- Phase 3: O = P @ V; Vt b128 from L2, P b128 from LDS ----
    {
        const int m  = wave >> 2;                // 0..1 (q-row half)
        const int d0 = (wave & 3) * 16;          // 0..48
        const uint16_t* vtrow = Vt + ((size_t)bh * kD + d0 + l16) * kS + lg * 8;
        const uint16_t* pbase = P_lds + (size_t)(m * 16 + l16) * kS;
        const int aswz = (l16 & 7) << 3;
        f32x4 acc0 = {0.f, 0.f, 0.f, 0.f};
        f32x4 acc1 = {0.f, 0.f, 0.f, 0.f};
        __builtin_amdgcn_s_setprio(1);
        #pragma unroll
        for (int kk = 0; kk < 32; kk += 2) {
            short8 a0 = *(const short8*)(pbase + ((kk * 32 + lg * 8) ^ aswz));
            short8 b0 = *(const short8*)(vtrow + kk * 32);
            acc0 = __builtin_amdgcn_mfma_f32_16x16x32_bf16(a0, b0, acc0, 0, 0, 0);
            short8 a1 = *(const short8*)(pbase + (((kk + 1) * 32 + lg * 8) ^ aswz));
            short8 b1 = *(const short8*)(vtrow + (kk + 1) * 32);
            acc1 = __builtin_amdgcn_mfma_f32_16x16x32_bf16(a1, b1, acc1, 0, 0, 0);
        }
        __builtin_amdgcn_s_setprio(0);
        f32x4 acc = acc0 + acc1;
        f32x4 invv = *(const f32x4*)(inv_lds + m * 16 + lg * 4);
        float* orow = Og + ((size_t)bh * kS + q0 + m * 16 + lg * 4) * kD + d0 + l16;
        #pragma unroll
        for (int r = 0; r < 4; ++r) orow[(size_t)r * kD] = acc[r] * invv[r];
    }
}

} // namespace

extern "C" void kernel_launch(void* const* d_in, const int* in_sizes, int n_in,
                              void* d_out, int out_size, void* d_ws, size_t ws_size,
                              hipStream_t stream) {
    const float* q = (const float*)d_in[0];
    const float* k = (const float*)d_in[1];
    const float* v = (const float*)d_in[2];
    const int*   m = (const int*)d_in[3];
    float* og = (float*)d_out;
    float* ag = og + (size_t)kBH * kS * kD;      // outputs concatenated: O then attn

    uint16_t* kb = (uint16_t*)d_ws;              // 16.78 MB bf16 K
    uint16_t* vt = kb + (size_t)kBH * kS * kD;   // 16.78 MB bf16 V^T [bh][d][k]

    conv_k_kernel<<<dim3(4096), dim3(256), 0, stream>>>(k, kb);
    transp_v_kernel<<<dim3(2048), dim3(256), 0, stream>>>(v, vt);
    sdpa_kernel<<<dim3(kBH * (kS / kQB)), dim3(512), 0, stream>>>(q, kb, vt, m, og, ag);
}